// Round 8
// baseline (130.955 us; speedup 1.0000x reference)
//
#include <hip/hip_runtime.h>
#include <math.h>

// Problem constants: h [B,T,D] fp32, k scalar fp32.
#define BB 8
#define TT 2048
#define DD 512
#define LL 16             // chunk length (t-steps)
#define CC (TT / LL)      // 128 chunks per b
#define D4 (DD / 4)       // 128 float4 lanes
#define SCT 64            // superchunk length (t-steps)
#define NSC (TT / SCT)    // 32 superchunks per b
#define CPS (SCT / LL)    // 4 chunks per superchunk

// ---------------------------------------------------------------------------
// R8 = R6 VERBATIM kernels, but kB is launched THREE times (kB is idempotent:
// reads h/ssum/send, deterministically overwrites out). Pure measurement
// round: dur_R8 - dur_R6 = 2 x (kB + dispatch gap). This pins the one free
// parameter every failed theory shared: how much of the 93.7 us is actually
// OUR kernel time vs harness fill/graph overhead.
// ---------------------------------------------------------------------------

typedef float floatx4 __attribute__((ext_vector_type(4)));

__device__ __forceinline__ float get_s(const float* kp) {
    float k = *kp;
    return (k > 20.0f) ? k : log1pf(expf(k));   // softplus, stable
}

// Kernel A (R6): block = (b, superchunk), 512 threads (8 waves).
__global__ __launch_bounds__(4 * D4) void kA_stats(
    const float* __restrict__ h, const float* __restrict__ kp,
    float* __restrict__ ssum, float* __restrict__ send)
{
    const int blk = blockIdx.x;
    const int b = blk / NSC, sc = blk % NSC;
    const int tid = threadIdx.x;
    const int jj  = tid >> 7;          // chunk within superchunk, 0..3
    const int col = tid & (D4 - 1);    // float4 column, 0..127
    const float s   = get_s(kp);
    const float a   = expf(-s);
    const float a16 = expf(-s * (float)LL);

    const float4* hp = reinterpret_cast<const float4*>(h)
                     + (size_t)(b * TT + sc * SCT + jj * LL) * D4 + col;

    float sx = 0.f, sy = 0.f, sz = 0.f, sw = 0.f;   // chunk sum
    float ex = 0.f, ey = 0.f, ez = 0.f, ew = 0.f;   // chunk decayed end
    #pragma unroll
    for (int i = 0; i < LL; i++) {
        float4 x = hp[(size_t)i * D4];
        sx += x.x; sy += x.y; sz += x.z; sw += x.w;
        ex = fmaf(a, ex, x.x);
        ey = fmaf(a, ey, x.y);
        ez = fmaf(a, ez, x.z);
        ew = fmaf(a, ew, x.w);
    }

    // ---- superchunk fold via LDS (same j-order as old serial fold) -------
    __shared__ float4 lsum[CPS][D4];   // 8 KB
    __shared__ float4 lend[CPS][D4];   // 8 KB
    lsum[jj][col] = make_float4(sx, sy, sz, sw);
    lend[jj][col] = make_float4(ex, ey, ez, ew);
    __syncthreads();

    if (jj == 0) {
        float Sx = 0.f, Sy = 0.f, Sz = 0.f, Sw = 0.f;
        float Ex = 0.f, Ey = 0.f, Ez = 0.f, Ew = 0.f;
        #pragma unroll
        for (int q = 0; q < CPS; q++) {
            float4 sv = lsum[q][col];
            float4 ev = lend[q][col];
            Sx += sv.x; Sy += sv.y; Sz += sv.z; Sw += sv.w;
            Ex = fmaf(a16, Ex, ev.x);
            Ey = fmaf(a16, Ey, ev.y);
            Ez = fmaf(a16, Ez, ev.z);
            Ew = fmaf(a16, Ew, ev.w);
        }
        const size_t si = (size_t)(b * NSC + sc) * D4 + col;
        reinterpret_cast<float4*>(ssum)[si] = make_float4(Sx, Sy, Sz, Sw);
        reinterpret_cast<float4*>(send)[si] = make_float4(Ex, Ey, Ez, Ew);
    }
}

// Kernel B (R6): block = (b, superchunk), 512 threads, h in registers,
// chunk stats via LDS, superchunk lookback batched+clamped.
__global__ __launch_bounds__(4 * D4, 2) void kB_out(
    const float* __restrict__ h, const float* __restrict__ kp,
    const float* __restrict__ ssum, const float* __restrict__ send,
    float* __restrict__ out)
{
    const int blk = blockIdx.x;
    const int b = blk / NSC, sc = blk % NSC;
    const int tid = threadIdx.x;
    const int jj  = tid >> 7;          // chunk within superchunk, 0..3
    const int col = tid & (D4 - 1);    // float4 column, 0..127
    const int gw   = (tid >> 6) & 1;   // wave within group, 0..1
    const int lane = tid & 63;
    const float s   = get_s(kp);
    const float a   = expf(-s);
    const float a16 = expf(-s * (float)LL);
    const float aSC = expf(-s * (float)SCT);

    const int t0 = sc * SCT + jj * LL;
    const float4* hp = reinterpret_cast<const float4*>(h)
                     + (size_t)(b * TT + t0) * D4 + col;

    __shared__ float4 lsum[CPS][D4];   // 8 KB: chunk sums
    __shared__ float4 lend[CPS][D4];   // 8 KB: chunk decayed ends
    __shared__ float part[CPS][2][LL]; // 512 B

    // ---- h chunk -> registers + chunk stats (same order as kA) -----------
    float4 hv[LL];                                   // 64 VGPRs
    float sx = 0.f, sy = 0.f, sz = 0.f, sw = 0.f;
    float ex = 0.f, ey = 0.f, ez = 0.f, ew = 0.f;
    #pragma unroll
    for (int i = 0; i < LL; i++) {
        float4 x = hp[(size_t)i * D4];
        hv[i] = x;
        sx += x.x; sy += x.y; sz += x.z; sw += x.w;
        ex = fmaf(a, ex, x.x);
        ey = fmaf(a, ey, x.y);
        ez = fmaf(a, ez, x.z);
        ew = fmaf(a, ew, x.w);
    }
    lsum[jj][col] = make_float4(sx, sy, sz, sw);
    lend[jj][col] = make_float4(ex, ey, ez, ew);

    float px = 0.f, py = 0.f, pz = 0.f, pw = 0.f;    // h[t0-1]
    if (t0 > 0) {
        float4 pv = *(hp - (ptrdiff_t)D4);
        px = pv.x; py = pv.y; pz = pv.z; pw = pv.w;
    }

    // ---- lookback level 1: superchunks before sc (batched, clamped) ------
    float cox = 0.f, coy = 0.f, coz = 0.f, cow = 0.f;   // cumsum offset
    float ccx = 0.f, ccy = 0.f, ccz = 0.f, ccw = 0.f;   // ctx entering state
    if (sc > 0) {
        const float4* ss4 = reinterpret_cast<const float4*>(ssum)
                          + (size_t)(b * NSC) * D4 + col;
        const float4* se4 = reinterpret_cast<const float4*>(send)
                          + (size_t)(b * NSC) * D4 + col;
        float w = 1.f;                      // aSC^d (descending weights)
        #pragma unroll
        for (int d = 0; d < NSC - 1; d++) {
            const int   q    = (d < sc) ? (sc - 1 - d) : 0;   // clamped addr
            const float live = (d < sc) ? 1.f : 0.f;
            float4 sv = ss4[(size_t)q * D4];
            float4 ev = se4[(size_t)q * D4];
            cox = fmaf(live, sv.x, cox);
            coy = fmaf(live, sv.y, coy);
            coz = fmaf(live, sv.z, coz);
            cow = fmaf(live, sv.w, cow);
            const float wl = w * live;
            ccx = fmaf(wl, ev.x, ccx);
            ccy = fmaf(wl, ev.y, ccy);
            ccz = fmaf(wl, ev.z, ccz);
            ccw = fmaf(wl, ev.w, ccw);
            w *= aSC;
        }
    }

    __syncthreads();   // chunk stats of all 4 groups visible in LDS

    // ---- lookback level 2: chunks before jj, from LDS --------------------
    if (jj > 0) {
        float cIx = 0.f, cIy = 0.f, cIz = 0.f, cIw = 0.f;
        float w = 1.f;                      // a16^d (descending weights)
        #pragma unroll
        for (int d = 0; d < CPS - 1; d++) {
            const int   q    = (d < jj) ? (jj - 1 - d) : 0;   // clamped addr
            const float live = (d < jj) ? 1.f : 0.f;
            float4 sv = lsum[q][col];
            float4 ev = lend[q][col];
            cox = fmaf(live, sv.x, cox);
            coy = fmaf(live, sv.y, coy);
            coz = fmaf(live, sv.z, coz);
            cow = fmaf(live, sv.w, cow);
            const float wl = w * live;
            cIx = fmaf(wl, ev.x, cIx);
            cIy = fmaf(wl, ev.y, cIy);
            cIz = fmaf(wl, ev.z, cIz);
            cIw = fmaf(wl, ev.w, cIw);
            w *= a16;
        }
        // ctx entering chunk = (superchunk carry) * a16^jj + intra part
        const float a32 = a16 * a16;
        const float wj  = (jj == 1) ? a16 : (jj == 2) ? a32 : a32 * a16;
        ccx = fmaf(wj, ccx, cIx);
        ccy = fmaf(wj, ccy, cIy);
        ccz = fmaf(wj, ccz, cIz);
        ccw = fmaf(wj, ccw, cIw);
    }

    // ---- pass A: cumsum chain from registers -----------------------------
    float r[LL];
    #pragma unroll
    for (int i = 0; i < LL; i++) {
        float4 x = hv[i];
        cox += x.x; coy += x.y; coz += x.z; cow += x.w;
        float dx = cox - px, dy = coy - py, dz = coz - pz, dw = cow - pw;
        r[i] = dx * dx + dy * dy + dz * dz + dw * dw;
        px = x.x; py = x.y; pz = x.z; pw = x.w;
    }

    // batched butterfly: 6 rounds x 16 independent values (within wave)
    #pragma unroll
    for (int m = 1; m < 64; m <<= 1) {
        #pragma unroll
        for (int i = 0; i < LL; i++) r[i] += __shfl_xor(r[i], m, 64);
    }
    if (lane == 0) {
        #pragma unroll
        for (int i = 0; i < LL; i++) part[jj][gw][i] = r[i];
    }
    __syncthreads();

    float mag[LL];
    #pragma unroll
    for (int i = 0; i < LL; i++) mag[i] = sqrtf(part[jj][0][i] + part[jj][1][i]);

    // ---- pass B: ctx recurrence from registers, non-temporal store -------
    floatx4* op = reinterpret_cast<floatx4*>(out)
                + (size_t)(b * TT + t0) * D4 + col;
    #pragma unroll
    for (int i = 0; i < LL; i++) {
        float4 x = hv[i];
        ccx = fmaf(a, ccx, x.x);
        ccy = fmaf(a, ccy, x.y);
        ccz = fmaf(a, ccz, x.z);
        ccw = fmaf(a, ccw, x.w);
        float m = mag[i];
        floatx4 o;
        o.x = fabsf(m * ccx); o.y = fabsf(m * ccy);
        o.z = fabsf(m * ccz); o.w = fabsf(m * ccw);
        __builtin_nontemporal_store(o, op + (size_t)i * D4);
    }
}

extern "C" void kernel_launch(void* const* d_in, const int* in_sizes, int n_in,
                              void* d_out, int out_size, void* d_ws, size_t ws_size,
                              hipStream_t stream) {
    const float* h  = (const float*)d_in[0];
    const float* kp = (const float*)d_in[1];
    float* out = (float*)d_out;

    const size_t NSb = (size_t)BB * NSC * DD;   // 128K floats = 512 KB each
    float* ssum = (float*)d_ws;
    float* send = ssum + NSb;

    kA_stats<<<dim3(BB * NSC), dim3(4 * D4), 0, stream>>>(h, kp, ssum, send);
    // ABLATION: kB launched 3x (idempotent). dur_R8 - dur_R6 = 2*(kB + gap).
    kB_out  <<<dim3(BB * NSC), dim3(4 * D4), 0, stream>>>(h, kp, ssum, send, out);
    kB_out  <<<dim3(BB * NSC), dim3(4 * D4), 0, stream>>>(h, kp, ssum, send, out);
    kB_out  <<<dim3(BB * NSC), dim3(4 * D4), 0, stream>>>(h, kp, ssum, send, out);
}

// Round 9
// 104.847 us; speedup vs baseline: 1.2490x; 1.2490x over previous
//
#include <hip/hip_runtime.h>
#include <math.h>

// Problem constants: h [B,T,D] fp32, k scalar fp32.
#define BB 8
#define TT 2048
#define DD 512
#define LL 16             // chunk length (t-steps)
#define CC (TT / LL)      // 128 chunks per b
#define D4 (DD / 4)       // 128 float4 lanes

typedef float floatx4 __attribute__((ext_vector_type(4)));

__device__ __forceinline__ float get_s(const float* kp) {
    float k = *kp;
    return (k > 20.0f) ? k : log1pf(expf(k));   // softplus, stable
}

// ---------------------------------------------------------------------------
// R9: both kernels flattened to chunk granularity, grid = 8*128 = 1024 blocks
// x 128 threads (4 blocks/CU, 8 waves/CU).
//
// R8's ablation pinned the budget: kA ~21.5 us (4x over roofline, invariant
// across 2 structures that both had grid=256 = 1 block/CU), kB ~16.6 us warm,
// gap ~2 us. This round tests the last structural hypothesis for kA (1
// block/CU + block-wide barrier coupling) while simplifying kB.
//
// kA1: chunk stats only. 16 independent loads accumulated in flight (no hv
//      array, no LDS, no barrier, no fold). Writes csum/cend (4 MB).
// kB': flat chunk-level lookback: weight of prior chunk q seen from chunk c
//      is a16^(c-1-q) (== the old nested aSC/a16 weights, proof in round
//      notes). Reads csum/cend (L2-resident) in 8-unrolled clamped batches.
//      Superchunk stats, in-block stat recompute, and one barrier all gone.
// ---------------------------------------------------------------------------

__global__ __launch_bounds__(D4) void kA_stats(
    const float* __restrict__ h, const float* __restrict__ kp,
    float* __restrict__ csum, float* __restrict__ cend)
{
    const int blk = blockIdx.x;
    const int b = blk / CC, c = blk % CC;
    const int tid = threadIdx.x;
    const float s = get_s(kp);
    const float a = expf(-s);

    const float4* hp = reinterpret_cast<const float4*>(h)
                     + (size_t)(b * TT + c * LL) * D4 + tid;

    float sx = 0.f, sy = 0.f, sz = 0.f, sw = 0.f;   // chunk sum
    float ex = 0.f, ey = 0.f, ez = 0.f, ew = 0.f;   // chunk decayed end
    #pragma unroll
    for (int i = 0; i < LL; i++) {
        float4 x = hp[(size_t)i * D4];
        sx += x.x; sy += x.y; sz += x.z; sw += x.w;
        ex = fmaf(a, ex, x.x);
        ey = fmaf(a, ey, x.y);
        ez = fmaf(a, ez, x.z);
        ew = fmaf(a, ew, x.w);
    }
    const size_t ci = (size_t)(b * CC + c) * D4 + tid;
    reinterpret_cast<float4*>(csum)[ci] = make_float4(sx, sy, sz, sw);
    reinterpret_cast<float4*>(cend)[ci] = make_float4(ex, ey, ez, ew);
}

__global__ __launch_bounds__(D4, 2) void kB_out(
    const float* __restrict__ h, const float* __restrict__ kp,
    const float* __restrict__ csum, const float* __restrict__ cend,
    float* __restrict__ out)
{
    const int blk = blockIdx.x;
    const int b = blk / CC, c = blk % CC;
    const int tid = threadIdx.x;
    const int wave = tid >> 6, lane = tid & 63;
    const float s   = get_s(kp);
    const float a   = expf(-s);
    const float a16 = expf(-s * (float)LL);

    const int t0 = c * LL;
    const float4* hp = reinterpret_cast<const float4*>(h)
                     + (size_t)(b * TT + t0) * D4 + tid;

    __shared__ float part[2][LL];

    // ---- h chunk -> registers (independent load batch) -------------------
    float4 hv[LL];                                   // 64 VGPRs
    #pragma unroll
    for (int i = 0; i < LL; i++) hv[i] = hp[(size_t)i * D4];

    float px = 0.f, py = 0.f, pz = 0.f, pw = 0.f;    // h[t0-1]
    if (t0 > 0) {
        float4 pv = *(hp - (ptrdiff_t)D4);
        px = pv.x; py = pv.y; pz = pv.z; pw = pv.w;
    }

    // ---- flat chunk-level lookback over chunks 0..c-1 --------------------
    // ccx entering own chunk = sum_q a16^(c-1-q) * E_q ; cox = sum_q S_q.
    // Runtime outer loop (block-uniform trip), 8-unrolled clamped inner so
    // each batch's 16 loads pipeline under one waitcnt.
    float cox = 0.f, coy = 0.f, coz = 0.f, cow = 0.f;   // cumsum offset
    float ccx = 0.f, ccy = 0.f, ccz = 0.f, ccw = 0.f;   // ctx entering state
    if (c > 0) {
        const float4* cs4 = reinterpret_cast<const float4*>(csum)
                          + (size_t)(b * CC) * D4 + tid;
        const float4* ce4 = reinterpret_cast<const float4*>(cend)
                          + (size_t)(b * CC) * D4 + tid;
        float w = 1.f;                      // a16^d (descending weights)
        for (int base = 0; base < c; base += 8) {
            #pragma unroll
            for (int u = 0; u < 8; u++) {
                const int   dd   = base + u;
                const int   q    = (dd < c) ? (c - 1 - dd) : 0;  // clamped
                const float live = (dd < c) ? 1.f : 0.f;
                float4 sv = cs4[(size_t)q * D4];
                float4 ev = ce4[(size_t)q * D4];
                cox = fmaf(live, sv.x, cox);
                coy = fmaf(live, sv.y, coy);
                coz = fmaf(live, sv.z, coz);
                cow = fmaf(live, sv.w, cow);
                const float wl = w * live;
                ccx = fmaf(wl, ev.x, ccx);
                ccy = fmaf(wl, ev.y, ccy);
                ccz = fmaf(wl, ev.z, ccz);
                ccw = fmaf(wl, ev.w, ccw);
                w *= a16;
            }
        }
    }

    // ---- pass A: cumsum chain from registers -----------------------------
    float r[LL];
    #pragma unroll
    for (int i = 0; i < LL; i++) {
        float4 x = hv[i];
        cox += x.x; coy += x.y; coz += x.z; cow += x.w;
        float dx = cox - px, dy = coy - py, dz = coz - pz, dw = cow - pw;
        r[i] = dx * dx + dy * dy + dz * dz + dw * dw;
        px = x.x; py = x.y; pz = x.z; pw = x.w;
    }

    // batched butterfly: 6 rounds x 16 independent values (within wave)
    #pragma unroll
    for (int m = 1; m < 64; m <<= 1) {
        #pragma unroll
        for (int i = 0; i < LL; i++) r[i] += __shfl_xor(r[i], m, 64);
    }
    if (lane == 0) {
        #pragma unroll
        for (int i = 0; i < LL; i++) part[wave][i] = r[i];
    }
    __syncthreads();

    float mag[LL];
    #pragma unroll
    for (int i = 0; i < LL; i++) mag[i] = sqrtf(part[0][i] + part[1][i]);

    // ---- pass B: ctx recurrence from registers, non-temporal store -------
    floatx4* op = reinterpret_cast<floatx4*>(out)
                + (size_t)(b * TT + t0) * D4 + tid;
    #pragma unroll
    for (int i = 0; i < LL; i++) {
        float4 x = hv[i];
        ccx = fmaf(a, ccx, x.x);
        ccy = fmaf(a, ccy, x.y);
        ccz = fmaf(a, ccz, x.z);
        ccw = fmaf(a, ccw, x.w);
        float m = mag[i];
        floatx4 o;
        o.x = fabsf(m * ccx); o.y = fabsf(m * ccy);
        o.z = fabsf(m * ccz); o.w = fabsf(m * ccw);
        __builtin_nontemporal_store(o, op + (size_t)i * D4);
    }
}

extern "C" void kernel_launch(void* const* d_in, const int* in_sizes, int n_in,
                              void* d_out, int out_size, void* d_ws, size_t ws_size,
                              hipStream_t stream) {
    const float* h  = (const float*)d_in[0];
    const float* kp = (const float*)d_in[1];
    float* out = (float*)d_out;

    const size_t NC = (size_t)BB * CC * DD;    // 512K floats = 2 MB each
    float* csum = (float*)d_ws;
    float* cend = csum + NC;

    kA_stats<<<dim3(BB * CC), dim3(D4), 0, stream>>>(h, kp, csum, cend);
    kB_out  <<<dim3(BB * CC), dim3(D4), 0, stream>>>(h, kp, csum, cend, out);
}

// Round 10
// 95.050 us; speedup vs baseline: 1.3777x; 1.1031x over previous
//
#include <hip/hip_runtime.h>
#include <math.h>

// Problem constants: h [B,T,D] fp32, k scalar fp32.
#define BB 8
#define TT 2048
#define DD 512
#define LL 16             // chunk length (t-steps)
#define CC (TT / LL)      // 128 chunks per b
#define D4 (DD / 4)       // 128 float4 lanes
#define SCT 64            // superchunk length (t-steps)
#define NSC (TT / SCT)    // 32 superchunks per b
#define CPS (SCT / LL)    // 4 chunks per superchunk

// ---------------------------------------------------------------------------
// R10 = R6 (best config, 93.7 us) with ONE change: the out store is a plain
// store, not __builtin_nontemporal_store. NT bypasses the 256 MB LLC and
// forces 30 MB of HBM write inside kB's timed window (~5 us). Regular stores
// leave out dirty in LLC (out 30 + h 32 + stats 1 MB all fit); the writeback
// moves off the kernel's critical path (absorbed, or drained in a later
// write-bound window at worst). Single-variable test of the in-window-HBM
// lever identified by the 9-round boundary-cost model.
// ---------------------------------------------------------------------------

__device__ __forceinline__ float get_s(const float* kp) {
    float k = *kp;
    return (k > 20.0f) ? k : log1pf(expf(k));   // softplus, stable
}

// Kernel A (R6): block = (b, superchunk), 512 threads (8 waves).
__global__ __launch_bounds__(4 * D4) void kA_stats(
    const float* __restrict__ h, const float* __restrict__ kp,
    float* __restrict__ ssum, float* __restrict__ send)
{
    const int blk = blockIdx.x;
    const int b = blk / NSC, sc = blk % NSC;
    const int tid = threadIdx.x;
    const int jj  = tid >> 7;          // chunk within superchunk, 0..3
    const int col = tid & (D4 - 1);    // float4 column, 0..127
    const float s   = get_s(kp);
    const float a   = expf(-s);
    const float a16 = expf(-s * (float)LL);

    const float4* hp = reinterpret_cast<const float4*>(h)
                     + (size_t)(b * TT + sc * SCT + jj * LL) * D4 + col;

    float sx = 0.f, sy = 0.f, sz = 0.f, sw = 0.f;   // chunk sum
    float ex = 0.f, ey = 0.f, ez = 0.f, ew = 0.f;   // chunk decayed end
    #pragma unroll
    for (int i = 0; i < LL; i++) {
        float4 x = hp[(size_t)i * D4];
        sx += x.x; sy += x.y; sz += x.z; sw += x.w;
        ex = fmaf(a, ex, x.x);
        ey = fmaf(a, ey, x.y);
        ez = fmaf(a, ez, x.z);
        ew = fmaf(a, ew, x.w);
    }

    // ---- superchunk fold via LDS (same j-order as old serial fold) -------
    __shared__ float4 lsum[CPS][D4];   // 8 KB
    __shared__ float4 lend[CPS][D4];   // 8 KB
    lsum[jj][col] = make_float4(sx, sy, sz, sw);
    lend[jj][col] = make_float4(ex, ey, ez, ew);
    __syncthreads();

    if (jj == 0) {
        float Sx = 0.f, Sy = 0.f, Sz = 0.f, Sw = 0.f;
        float Ex = 0.f, Ey = 0.f, Ez = 0.f, Ew = 0.f;
        #pragma unroll
        for (int q = 0; q < CPS; q++) {
            float4 sv = lsum[q][col];
            float4 ev = lend[q][col];
            Sx += sv.x; Sy += sv.y; Sz += sv.z; Sw += sv.w;
            Ex = fmaf(a16, Ex, ev.x);
            Ey = fmaf(a16, Ey, ev.y);
            Ez = fmaf(a16, Ez, ev.z);
            Ew = fmaf(a16, Ew, ev.w);
        }
        const size_t si = (size_t)(b * NSC + sc) * D4 + col;
        reinterpret_cast<float4*>(ssum)[si] = make_float4(Sx, Sy, Sz, Sw);
        reinterpret_cast<float4*>(send)[si] = make_float4(Ex, Ey, Ez, Ew);
    }
}

// Kernel B (R6): block = (b, superchunk), 512 threads, h in registers,
// chunk stats via LDS, superchunk lookback batched+clamped. Plain out store.
__global__ __launch_bounds__(4 * D4, 2) void kB_out(
    const float* __restrict__ h, const float* __restrict__ kp,
    const float* __restrict__ ssum, const float* __restrict__ send,
    float* __restrict__ out)
{
    const int blk = blockIdx.x;
    const int b = blk / NSC, sc = blk % NSC;
    const int tid = threadIdx.x;
    const int jj  = tid >> 7;          // chunk within superchunk, 0..3
    const int col = tid & (D4 - 1);    // float4 column, 0..127
    const int gw   = (tid >> 6) & 1;   // wave within group, 0..1
    const int lane = tid & 63;
    const float s   = get_s(kp);
    const float a   = expf(-s);
    const float a16 = expf(-s * (float)LL);
    const float aSC = expf(-s * (float)SCT);

    const int t0 = sc * SCT + jj * LL;
    const float4* hp = reinterpret_cast<const float4*>(h)
                     + (size_t)(b * TT + t0) * D4 + col;

    __shared__ float4 lsum[CPS][D4];   // 8 KB: chunk sums
    __shared__ float4 lend[CPS][D4];   // 8 KB: chunk decayed ends
    __shared__ float part[CPS][2][LL]; // 512 B

    // ---- h chunk -> registers + chunk stats (same order as kA) -----------
    float4 hv[LL];                                   // 64 VGPRs
    float sx = 0.f, sy = 0.f, sz = 0.f, sw = 0.f;
    float ex = 0.f, ey = 0.f, ez = 0.f, ew = 0.f;
    #pragma unroll
    for (int i = 0; i < LL; i++) {
        float4 x = hp[(size_t)i * D4];
        hv[i] = x;
        sx += x.x; sy += x.y; sz += x.z; sw += x.w;
        ex = fmaf(a, ex, x.x);
        ey = fmaf(a, ey, x.y);
        ez = fmaf(a, ez, x.z);
        ew = fmaf(a, ew, x.w);
    }
    lsum[jj][col] = make_float4(sx, sy, sz, sw);
    lend[jj][col] = make_float4(ex, ey, ez, ew);

    float px = 0.f, py = 0.f, pz = 0.f, pw = 0.f;    // h[t0-1]
    if (t0 > 0) {
        float4 pv = *(hp - (ptrdiff_t)D4);
        px = pv.x; py = pv.y; pz = pv.z; pw = pv.w;
    }

    // ---- lookback level 1: superchunks before sc (batched, clamped) ------
    float cox = 0.f, coy = 0.f, coz = 0.f, cow = 0.f;   // cumsum offset
    float ccx = 0.f, ccy = 0.f, ccz = 0.f, ccw = 0.f;   // ctx entering state
    if (sc > 0) {
        const float4* ss4 = reinterpret_cast<const float4*>(ssum)
                          + (size_t)(b * NSC) * D4 + col;
        const float4* se4 = reinterpret_cast<const float4*>(send)
                          + (size_t)(b * NSC) * D4 + col;
        float w = 1.f;                      // aSC^d (descending weights)
        #pragma unroll
        for (int d = 0; d < NSC - 1; d++) {
            const int   q    = (d < sc) ? (sc - 1 - d) : 0;   // clamped addr
            const float live = (d < sc) ? 1.f : 0.f;
            float4 sv = ss4[(size_t)q * D4];
            float4 ev = se4[(size_t)q * D4];
            cox = fmaf(live, sv.x, cox);
            coy = fmaf(live, sv.y, coy);
            coz = fmaf(live, sv.z, coz);
            cow = fmaf(live, sv.w, cow);
            const float wl = w * live;
            ccx = fmaf(wl, ev.x, ccx);
            ccy = fmaf(wl, ev.y, ccy);
            ccz = fmaf(wl, ev.z, ccz);
            ccw = fmaf(wl, ev.w, ccw);
            w *= aSC;
        }
    }

    __syncthreads();   // chunk stats of all 4 groups visible in LDS

    // ---- lookback level 2: chunks before jj, from LDS --------------------
    if (jj > 0) {
        float cIx = 0.f, cIy = 0.f, cIz = 0.f, cIw = 0.f;
        float w = 1.f;                      // a16^d (descending weights)
        #pragma unroll
        for (int d = 0; d < CPS - 1; d++) {
            const int   q    = (d < jj) ? (jj - 1 - d) : 0;   // clamped addr
            const float live = (d < jj) ? 1.f : 0.f;
            float4 sv = lsum[q][col];
            float4 ev = lend[q][col];
            cox = fmaf(live, sv.x, cox);
            coy = fmaf(live, sv.y, coy);
            coz = fmaf(live, sv.z, coz);
            cow = fmaf(live, sv.w, cow);
            const float wl = w * live;
            cIx = fmaf(wl, ev.x, cIx);
            cIy = fmaf(wl, ev.y, cIy);
            cIz = fmaf(wl, ev.z, cIz);
            cIw = fmaf(wl, ev.w, cIw);
            w *= a16;
        }
        // ctx entering chunk = (superchunk carry) * a16^jj + intra part
        const float a32 = a16 * a16;
        const float wj  = (jj == 1) ? a16 : (jj == 2) ? a32 : a32 * a16;
        ccx = fmaf(wj, ccx, cIx);
        ccy = fmaf(wj, ccy, cIy);
        ccz = fmaf(wj, ccz, cIz);
        ccw = fmaf(wj, ccw, cIw);
    }

    // ---- pass A: cumsum chain from registers -----------------------------
    float r[LL];
    #pragma unroll
    for (int i = 0; i < LL; i++) {
        float4 x = hv[i];
        cox += x.x; coy += x.y; coz += x.z; cow += x.w;
        float dx = cox - px, dy = coy - py, dz = coz - pz, dw = cow - pw;
        r[i] = dx * dx + dy * dy + dz * dz + dw * dw;
        px = x.x; py = x.y; pz = x.z; pw = x.w;
    }

    // batched butterfly: 6 rounds x 16 independent values (within wave)
    #pragma unroll
    for (int m = 1; m < 64; m <<= 1) {
        #pragma unroll
        for (int i = 0; i < LL; i++) r[i] += __shfl_xor(r[i], m, 64);
    }
    if (lane == 0) {
        #pragma unroll
        for (int i = 0; i < LL; i++) part[jj][gw][i] = r[i];
    }
    __syncthreads();

    float mag[LL];
    #pragma unroll
    for (int i = 0; i < LL; i++) mag[i] = sqrtf(part[jj][0][i] + part[jj][1][i]);

    // ---- pass B: ctx recurrence from registers, PLAIN store (LLC-absorbed)
    float4* op = reinterpret_cast<float4*>(out)
               + (size_t)(b * TT + t0) * D4 + col;
    #pragma unroll
    for (int i = 0; i < LL; i++) {
        float4 x = hv[i];
        ccx = fmaf(a, ccx, x.x);
        ccy = fmaf(a, ccy, x.y);
        ccz = fmaf(a, ccz, x.z);
        ccw = fmaf(a, ccw, x.w);
        float m = mag[i];
        float4 o;
        o.x = fabsf(m * ccx); o.y = fabsf(m * ccy);
        o.z = fabsf(m * ccz); o.w = fabsf(m * ccw);
        op[(size_t)i * D4] = o;
    }
}

extern "C" void kernel_launch(void* const* d_in, const int* in_sizes, int n_in,
                              void* d_out, int out_size, void* d_ws, size_t ws_size,
                              hipStream_t stream) {
    const float* h  = (const float*)d_in[0];
    const float* kp = (const float*)d_in[1];
    float* out = (float*)d_out;

    const size_t NSb = (size_t)BB * NSC * DD;   // 128K floats = 512 KB each
    float* ssum = (float*)d_ws;
    float* send = ssum + NSb;

    kA_stats<<<dim3(BB * NSC), dim3(4 * D4), 0, stream>>>(h, kp, ssum, send);
    kB_out  <<<dim3(BB * NSC), dim3(4 * D4), 0, stream>>>(h, kp, ssum, send, out);
}

// Round 11
// 94.131 us; speedup vs baseline: 1.3912x; 1.0098x over previous
//
#include <hip/hip_runtime.h>
#include <math.h>

// Problem constants: h [B,T,D] fp32, k scalar fp32.
#define BB 8
#define TT 2048
#define DD 512
#define LL 16             // chunk length (t-steps)
#define CC (TT / LL)      // 128 chunks per b
#define D4 (DD / 4)       // 128 float4 lanes
#define SCT 64            // superchunk length (t-steps)
#define NSC (TT / SCT)    // 32 superchunks per b
#define CPS (SCT / LL)    // 4 chunks per superchunk

// ---------------------------------------------------------------------------
// R11 = R6 VERBATIM (best measured config, 93.7 us), reverting R10's plain
// store back to __builtin_nontemporal_store (R10: +1.3 us).
//
// Final configuration after the 10-round campaign:
//  kA: block = (b, superchunk), 512 thr; per-128-thr-group chunk stats
//      (dep chain 16 loads), LDS fold -> ssum/send only.
//  kB: block = (b, superchunk), 512 thr; h in registers (no LDS stash),
//      chunk stats recomputed in-block + shared via LDS (chunk lookback in
//      LDS, not L2), superchunk lookback = fixed-trip clamped batch,
//      wave butterfly norm, NT out store.
// Accounting (validated by R3 calibration + R8 duplication ablation):
//  fill 44 + memset ~5 + 2 boundaries ~10 + kA ~11 + kB ~13.5 = ~93.5.
// ---------------------------------------------------------------------------

typedef float floatx4 __attribute__((ext_vector_type(4)));

__device__ __forceinline__ float get_s(const float* kp) {
    float k = *kp;
    return (k > 20.0f) ? k : log1pf(expf(k));   // softplus, stable
}

// Kernel A: block = (b, superchunk), 512 threads (8 waves).
__global__ __launch_bounds__(4 * D4) void kA_stats(
    const float* __restrict__ h, const float* __restrict__ kp,
    float* __restrict__ ssum, float* __restrict__ send)
{
    const int blk = blockIdx.x;
    const int b = blk / NSC, sc = blk % NSC;
    const int tid = threadIdx.x;
    const int jj  = tid >> 7;          // chunk within superchunk, 0..3
    const int col = tid & (D4 - 1);    // float4 column, 0..127
    const float s   = get_s(kp);
    const float a   = expf(-s);
    const float a16 = expf(-s * (float)LL);

    const float4* hp = reinterpret_cast<const float4*>(h)
                     + (size_t)(b * TT + sc * SCT + jj * LL) * D4 + col;

    float sx = 0.f, sy = 0.f, sz = 0.f, sw = 0.f;   // chunk sum
    float ex = 0.f, ey = 0.f, ez = 0.f, ew = 0.f;   // chunk decayed end
    #pragma unroll
    for (int i = 0; i < LL; i++) {
        float4 x = hp[(size_t)i * D4];
        sx += x.x; sy += x.y; sz += x.z; sw += x.w;
        ex = fmaf(a, ex, x.x);
        ey = fmaf(a, ey, x.y);
        ez = fmaf(a, ez, x.z);
        ew = fmaf(a, ew, x.w);
    }

    // ---- superchunk fold via LDS (same j-order as old serial fold) -------
    __shared__ float4 lsum[CPS][D4];   // 8 KB
    __shared__ float4 lend[CPS][D4];   // 8 KB
    lsum[jj][col] = make_float4(sx, sy, sz, sw);
    lend[jj][col] = make_float4(ex, ey, ez, ew);
    __syncthreads();

    if (jj == 0) {
        float Sx = 0.f, Sy = 0.f, Sz = 0.f, Sw = 0.f;
        float Ex = 0.f, Ey = 0.f, Ez = 0.f, Ew = 0.f;
        #pragma unroll
        for (int q = 0; q < CPS; q++) {
            float4 sv = lsum[q][col];
            float4 ev = lend[q][col];
            Sx += sv.x; Sy += sv.y; Sz += sv.z; Sw += sv.w;
            Ex = fmaf(a16, Ex, ev.x);
            Ey = fmaf(a16, Ey, ev.y);
            Ez = fmaf(a16, Ez, ev.z);
            Ew = fmaf(a16, Ew, ev.w);
        }
        const size_t si = (size_t)(b * NSC + sc) * D4 + col;
        reinterpret_cast<float4*>(ssum)[si] = make_float4(Sx, Sy, Sz, Sw);
        reinterpret_cast<float4*>(send)[si] = make_float4(Ex, Ey, Ez, Ew);
    }
}

// Kernel B: block = (b, superchunk), 512 threads, h in registers,
// chunk stats via LDS, superchunk lookback batched+clamped, NT out store.
__global__ __launch_bounds__(4 * D4, 2) void kB_out(
    const float* __restrict__ h, const float* __restrict__ kp,
    const float* __restrict__ ssum, const float* __restrict__ send,
    float* __restrict__ out)
{
    const int blk = blockIdx.x;
    const int b = blk / NSC, sc = blk % NSC;
    const int tid = threadIdx.x;
    const int jj  = tid >> 7;          // chunk within superchunk, 0..3
    const int col = tid & (D4 - 1);    // float4 column, 0..127
    const int gw   = (tid >> 6) & 1;   // wave within group, 0..1
    const int lane = tid & 63;
    const float s   = get_s(kp);
    const float a   = expf(-s);
    const float a16 = expf(-s * (float)LL);
    const float aSC = expf(-s * (float)SCT);

    const int t0 = sc * SCT + jj * LL;
    const float4* hp = reinterpret_cast<const float4*>(h)
                     + (size_t)(b * TT + t0) * D4 + col;

    __shared__ float4 lsum[CPS][D4];   // 8 KB: chunk sums
    __shared__ float4 lend[CPS][D4];   // 8 KB: chunk decayed ends
    __shared__ float part[CPS][2][LL]; // 512 B

    // ---- h chunk -> registers + chunk stats (same order as kA) -----------
    float4 hv[LL];                                   // 64 VGPRs
    float sx = 0.f, sy = 0.f, sz = 0.f, sw = 0.f;
    float ex = 0.f, ey = 0.f, ez = 0.f, ew = 0.f;
    #pragma unroll
    for (int i = 0; i < LL; i++) {
        float4 x = hp[(size_t)i * D4];
        hv[i] = x;
        sx += x.x; sy += x.y; sz += x.z; sw += x.w;
        ex = fmaf(a, ex, x.x);
        ey = fmaf(a, ey, x.y);
        ez = fmaf(a, ez, x.z);
        ew = fmaf(a, ew, x.w);
    }
    lsum[jj][col] = make_float4(sx, sy, sz, sw);
    lend[jj][col] = make_float4(ex, ey, ez, ew);

    float px = 0.f, py = 0.f, pz = 0.f, pw = 0.f;    // h[t0-1]
    if (t0 > 0) {
        float4 pv = *(hp - (ptrdiff_t)D4);
        px = pv.x; py = pv.y; pz = pv.z; pw = pv.w;
    }

    // ---- lookback level 1: superchunks before sc (batched, clamped) ------
    float cox = 0.f, coy = 0.f, coz = 0.f, cow = 0.f;   // cumsum offset
    float ccx = 0.f, ccy = 0.f, ccz = 0.f, ccw = 0.f;   // ctx entering state
    if (sc > 0) {
        const float4* ss4 = reinterpret_cast<const float4*>(ssum)
                          + (size_t)(b * NSC) * D4 + col;
        const float4* se4 = reinterpret_cast<const float4*>(send)
                          + (size_t)(b * NSC) * D4 + col;
        float w = 1.f;                      // aSC^d (descending weights)
        #pragma unroll
        for (int d = 0; d < NSC - 1; d++) {
            const int   q    = (d < sc) ? (sc - 1 - d) : 0;   // clamped addr
            const float live = (d < sc) ? 1.f : 0.f;
            float4 sv = ss4[(size_t)q * D4];
            float4 ev = se4[(size_t)q * D4];
            cox = fmaf(live, sv.x, cox);
            coy = fmaf(live, sv.y, coy);
            coz = fmaf(live, sv.z, coz);
            cow = fmaf(live, sv.w, cow);
            const float wl = w * live;
            ccx = fmaf(wl, ev.x, ccx);
            ccy = fmaf(wl, ev.y, ccy);
            ccz = fmaf(wl, ev.z, ccz);
            ccw = fmaf(wl, ev.w, ccw);
            w *= aSC;
        }
    }

    __syncthreads();   // chunk stats of all 4 groups visible in LDS

    // ---- lookback level 2: chunks before jj, from LDS --------------------
    if (jj > 0) {
        float cIx = 0.f, cIy = 0.f, cIz = 0.f, cIw = 0.f;
        float w = 1.f;                      // a16^d (descending weights)
        #pragma unroll
        for (int d = 0; d < CPS - 1; d++) {
            const int   q    = (d < jj) ? (jj - 1 - d) : 0;   // clamped addr
            const float live = (d < jj) ? 1.f : 0.f;
            float4 sv = lsum[q][col];
            float4 ev = lend[q][col];
            cox = fmaf(live, sv.x, cox);
            coy = fmaf(live, sv.y, coy);
            coz = fmaf(live, sv.z, coz);
            cow = fmaf(live, sv.w, cow);
            const float wl = w * live;
            cIx = fmaf(wl, ev.x, cIx);
            cIy = fmaf(wl, ev.y, cIy);
            cIz = fmaf(wl, ev.z, cIz);
            cIw = fmaf(wl, ev.w, cIw);
            w *= a16;
        }
        // ctx entering chunk = (superchunk carry) * a16^jj + intra part
        const float a32 = a16 * a16;
        const float wj  = (jj == 1) ? a16 : (jj == 2) ? a32 : a32 * a16;
        ccx = fmaf(wj, ccx, cIx);
        ccy = fmaf(wj, ccy, cIy);
        ccz = fmaf(wj, ccz, cIz);
        ccw = fmaf(wj, ccw, cIw);
    }

    // ---- pass A: cumsum chain from registers -----------------------------
    float r[LL];
    #pragma unroll
    for (int i = 0; i < LL; i++) {
        float4 x = hv[i];
        cox += x.x; coy += x.y; coz += x.z; cow += x.w;
        float dx = cox - px, dy = coy - py, dz = coz - pz, dw = cow - pw;
        r[i] = dx * dx + dy * dy + dz * dz + dw * dw;
        px = x.x; py = x.y; pz = x.z; pw = x.w;
    }

    // batched butterfly: 6 rounds x 16 independent values (within wave)
    #pragma unroll
    for (int m = 1; m < 64; m <<= 1) {
        #pragma unroll
        for (int i = 0; i < LL; i++) r[i] += __shfl_xor(r[i], m, 64);
    }
    if (lane == 0) {
        #pragma unroll
        for (int i = 0; i < LL; i++) part[jj][gw][i] = r[i];
    }
    __syncthreads();

    float mag[LL];
    #pragma unroll
    for (int i = 0; i < LL; i++) mag[i] = sqrtf(part[jj][0][i] + part[jj][1][i]);

    // ---- pass B: ctx recurrence from registers, non-temporal store -------
    floatx4* op = reinterpret_cast<floatx4*>(out)
                + (size_t)(b * TT + t0) * D4 + col;
    #pragma unroll
    for (int i = 0; i < LL; i++) {
        float4 x = hv[i];
        ccx = fmaf(a, ccx, x.x);
        ccy = fmaf(a, ccy, x.y);
        ccz = fmaf(a, ccz, x.z);
        ccw = fmaf(a, ccw, x.w);
        float m = mag[i];
        floatx4 o;
        o.x = fabsf(m * ccx); o.y = fabsf(m * ccy);
        o.z = fabsf(m * ccz); o.w = fabsf(m * ccw);
        __builtin_nontemporal_store(o, op + (size_t)i * D4);
    }
}

extern "C" void kernel_launch(void* const* d_in, const int* in_sizes, int n_in,
                              void* d_out, int out_size, void* d_ws, size_t ws_size,
                              hipStream_t stream) {
    const float* h  = (const float*)d_in[0];
    const float* kp = (const float*)d_in[1];
    float* out = (float*)d_out;

    const size_t NSb = (size_t)BB * NSC * DD;   // 128K floats = 512 KB each
    float* ssum = (float*)d_ws;
    float* send = ssum + NSb;

    kA_stats<<<dim3(BB * NSC), dim3(4 * D4), 0, stream>>>(h, kp, ssum, send);
    kB_out  <<<dim3(BB * NSC), dim3(4 * D4), 0, stream>>>(h, kp, ssum, send, out);
}